// Round 1
// baseline (1280.392 us; speedup 1.0000x reference)
//
#include <hip/hip_runtime.h>
#include <hip/hip_bf16.h>
#include <stdint.h>

// ---------------------------------------------------------------------------
// GCN: h1 = relu(adj @ (x @ W1) + b1); h2 = relu(adj @ (h1 @ W2) + b2)
//      out[b] = (sum_{n<len[b]} h2[b,n,:] / len[b]) @ Wl + bl
// B=64, N=1024, NFEAT=512, NHID1=1024, NHID2=512
//
// All GEMMs in NT form: C[m][n] = sum_k A[m][k] * Bt[n][k]
//   A row-major [M,K], Bt row-major [N,K]. Both LDS tiles [rows][K-chunk],
//   both MFMA fragments contiguous ds_read_b128 (m92/m97 verified layout).
// ---------------------------------------------------------------------------

typedef short bf16x8 __attribute__((ext_vector_type(8)));
typedef short s16x4 __attribute__((ext_vector_type(4)));
typedef float f32x4 __attribute__((ext_vector_type(4)));

#define BM 128
#define BN 128
#define BK 32

__device__ __forceinline__ unsigned short f2bf(float f) {
    union { float f; unsigned u; } v; v.f = f;
    unsigned r = v.u + 0x7fffu + ((v.u >> 16) & 1u);   // RNE
    return (unsigned short)(r >> 16);
}
__device__ __forceinline__ float bf2f(unsigned short h) {
    union { unsigned u; float f; } v; v.u = ((unsigned)h) << 16;
    return v.f;
}

typedef const __attribute__((address_space(1))) void* gp1_t;
typedef __attribute__((address_space(3))) void* lp3_t;

__device__ __forceinline__ void ldsload16(const void* g, void* l) {
    // dest = wave-uniform LDS base + lane*16 (HW semantics)
    __builtin_amdgcn_global_load_lds((gp1_t)(uintptr_t)g,
                                     (lp3_t)(unsigned)(uintptr_t)l,
                                     16, 0, 0);
}

// NT GEMM: C = A(MxK,row) * Bt(NxK,row)^T, bf16 in/out, fp32 accumulate.
// SPLIT:  C index (m, nf) -> nf=b*1024+n stored at b*splitStride + m*1024 + n
// !SPLIT: C index (m, n)  -> z*cStride + m*N + n, optional bias[n] + relu
template<bool BIASRELU, bool SPLIT>
__global__ __launch_bounds__(256, 3)
void gemm_nt(const short* __restrict__ A, const short* __restrict__ B,
             short* __restrict__ C, const float* __restrict__ bias,
             int M, int N, int K,
             long long aStride, long long bStride, long long cStride,
             long long splitStride)
{
    __shared__ short As[BM * BK];   // 8 KB
    __shared__ short Bs[BN * BK];   // 8 KB

    const int tid  = threadIdx.x;
    const int wave = tid >> 6;
    const int lane = tid & 63;
    const int wm   = wave >> 1;       // 0..1
    const int wn   = wave & 1;        // 0..1
    const int quad = lane >> 4;       // 0..3
    const int l16  = lane & 15;

    const int bM = blockIdx.y * BM;
    const int bN = blockIdx.x * BN;
    const int z  = blockIdx.z;
    A += (long long)z * aStride;
    B += (long long)z * bStride;

    // staging: each lane loads 16B (8 bf16); wave covers 16 rows x 32 cols
    const int srow = lane >> 2;        // 0..15
    const int scol = (lane & 3) * 8;   // 0,8,16,24
    const short* Ag = A + (long long)(bM + wave * 16 + srow) * K + scol;
    const short* Bg = B + (long long)(bN + wave * 16 + srow) * K + scol;
    short* Asl = &As[(wave * 16) * BK];   // wave-uniform LDS base
    short* Bsl = &Bs[(wave * 16) * BK];

    f32x4 acc[4][4];
#pragma unroll
    for (int i = 0; i < 4; i++)
#pragma unroll
        for (int j = 0; j < 4; j++) acc[i][j] = (f32x4)0.0f;

    for (int k0 = 0; k0 < K; k0 += BK) {
        ldsload16(Ag + k0, Asl);
        ldsload16(Ag + (long long)64 * K + k0, Asl + 64 * BK);
        ldsload16(Bg + k0, Bsl);
        ldsload16(Bg + (long long)64 * K + k0, Bsl + 64 * BK);
        __syncthreads();

        bf16x8 af[4], bfr[4];
#pragma unroll
        for (int i = 0; i < 4; i++)
            af[i] = *(const bf16x8*)&As[(wm * 64 + i * 16 + l16) * BK + quad * 8];
#pragma unroll
        for (int j = 0; j < 4; j++)
            bfr[j] = *(const bf16x8*)&Bs[(wn * 64 + j * 16 + l16) * BK + quad * 8];
#pragma unroll
        for (int i = 0; i < 4; i++)
#pragma unroll
            for (int j = 0; j < 4; j++)
                acc[i][j] = __builtin_amdgcn_mfma_f32_16x16x32_bf16(
                    af[i], bfr[j], acc[i][j], 0, 0, 0);
        __syncthreads();
    }

    // Epilogue. C/D layout: col(n)=lane&15, row(m)=quad*4+reg  [m89/m91]
#pragma unroll
    for (int i = 0; i < 4; i++) {
        const int row0 = bM + wm * 64 + i * 16 + quad * 4;
#pragma unroll
        for (int j = 0; j < 4; j++) {
            const int col = bN + wn * 64 + j * 16 + l16;
            float bv = 0.0f;
            if (BIASRELU) bv = bias[col];
#pragma unroll
            for (int r = 0; r < 4; r++) {
                float val = acc[i][j][r];
                if (BIASRELU) val = fmaxf(val + bv, 0.0f);
                long long addr;
                if (SPLIT) {
                    const int bb = col >> 10;
                    const int n  = col & 1023;
                    addr = (long long)bb * splitStride
                         + (long long)(row0 + r) * 1024 + n;
                } else {
                    addr = (long long)z * cStride
                         + (long long)(row0 + r) * N + col;
                }
                C[addr] = (short)f2bf(val);
            }
        }
    }
}

__global__ void cvt_f32_bf16(const float4* __restrict__ in,
                             s16x4* __restrict__ out, int n4)
{
    int i = blockIdx.x * 256 + threadIdx.x;
    if (i < n4) {
        float4 v = in[i];
        s16x4 o;
        o.x = (short)f2bf(v.x); o.y = (short)f2bf(v.y);
        o.z = (short)f2bf(v.z); o.w = (short)f2bf(v.w);
        out[i] = o;
    }
}

// in[R][C] fp32 -> out[C][R] bf16
__global__ void transpose_cvt(const float* __restrict__ in,
                              short* __restrict__ out, int R, int C)
{
    int o = blockIdx.x * 256 + threadIdx.x;
    if (o < R * C) {
        int c = o / R;
        int r = o - c * R;
        out[o] = (short)f2bf(in[(long long)r * C + c]);
    }
}

// h2 [64][1024][512] bf16 -> out[b] = (sum_{n<len} h2[b,n,:] / len) . Wl + bl
__global__ void pool_final(const short* __restrict__ h2,
                           const int* __restrict__ length,
                           const float* __restrict__ Wl,
                           const float* __restrict__ bl,
                           float* __restrict__ out)
{
    const int b = blockIdx.x;
    const int t = threadIdx.x;   // 512 threads, one per hidden channel
    const int len = length[b];
    const short* p = h2 + (long long)b * 1024 * 512;
    float acc = 0.0f;
    for (int n = 0; n < len; n++)
        acc += bf2f((unsigned short)p[(long long)n * 512 + t]);
    float v = acc * Wl[t];

    __shared__ float wsum[8];
#pragma unroll
    for (int off = 32; off > 0; off >>= 1) v += __shfl_down(v, off);
    if ((t & 63) == 0) wsum[t >> 6] = v;
    __syncthreads();
    if (t == 0) {
        float s = 0.0f;
#pragma unroll
        for (int w = 0; w < 8; w++) s += wsum[w];
        out[b] = s / (float)len + bl[0];
    }
}

extern "C" void kernel_launch(void* const* d_in, const int* in_sizes, int n_in,
                              void* d_out, int out_size, void* d_ws, size_t ws_size,
                              hipStream_t stream)
{
    const float* x    = (const float*)d_in[0];   // [64,1024,512]
    const float* adj  = (const float*)d_in[1];   // [64,1024,1024]
    const int*   len  = (const int*)d_in[2];     // [64]
    const float* W1   = (const float*)d_in[3];   // [512,1024]
    const float* b1   = (const float*)d_in[4];   // [1024]
    const float* W2   = (const float*)d_in[5];   // [1024,512]
    const float* b2   = (const float*)d_in[6];   // [512]
    const float* Wl   = (const float*)d_in[7];   // [512]
    const float* bl   = (const float*)d_in[8];   // [1]
    float* out = (float*)d_out;

    // workspace layout (450 MiB total)
    char* ws = (char*)d_ws;
    short* adjB  = (short*)(ws);                         // 134217728 B
    short* xS2T  = (short*)(ws + 134217728LL);           //  67108864 B (x_bf16, later S2T)
    short* W1T   = (short*)(ws + 201326592LL);           //   1048576 B
    short* W2T   = (short*)(ws + 202375168LL);           //   1048576 B
    short* S1Th2 = (short*)(ws + 203423744LL);           // 134217728 B (S1T, later h2)
    short* h1    = (short*)(ws + 337641472LL);           // 134217728 B

    // conversions
    cvt_f32_bf16<<<65536, 256, 0, stream>>>((const float4*)adj, (s16x4*)adjB, 16777216);
    cvt_f32_bf16<<<32768, 256, 0, stream>>>((const float4*)x,   (s16x4*)xS2T,  8388608);
    transpose_cvt<<<2048, 256, 0, stream>>>(W1, W1T, 512, 1024);   // -> [1024,512]
    transpose_cvt<<<2048, 256, 0, stream>>>(W2, W2T, 1024, 512);   // -> [512,1024]

    // GEMM1 (transposed): S1T[b][h][n] = sum_f W1T[h][f] * x[b*1024+n][f]
    gemm_nt<false, true><<<dim3(512, 8, 1), 256, 0, stream>>>(
        W1T, xS2T, S1Th2, nullptr, 1024, 65536, 512, 0, 0, 0, 1048576LL);

    // GEMM2: h1[b][i][h] = relu(sum_j adj[b][i][j] * S1T[b][h][j] + b1[h])
    gemm_nt<true, false><<<dim3(8, 8, 64), 256, 0, stream>>>(
        adjB, S1Th2, h1, b1, 1024, 1024, 1024, 1048576LL, 1048576LL, 1048576LL, 0);

    // GEMM3 (transposed): S2T[b][h2][n] = sum_h W2T[h2][h] * h1[b*1024+n][h]
    gemm_nt<false, true><<<dim3(512, 4, 1), 256, 0, stream>>>(
        W2T, h1, xS2T, nullptr, 512, 65536, 1024, 0, 0, 0, 524288LL);

    // GEMM4: h2[b][i][h2] = relu(sum_j adj[b][i][j] * S2T[b][h2][j] + b2[h2])
    gemm_nt<true, false><<<dim3(4, 8, 64), 256, 0, stream>>>(
        adjB, xS2T, S1Th2, b2, 1024, 512, 1024, 1048576LL, 524288LL, 524288LL, 0);

    // pool + final linear
    pool_final<<<64, 512, 0, stream>>>(S1Th2, len, Wl, bl, out);
}

// Round 2
// 1026.712 us; speedup vs baseline: 1.2471x; 1.2471x over previous
//
#include <hip/hip_runtime.h>
#include <hip/hip_bf16.h>
#include <stdint.h>

// ---------------------------------------------------------------------------
// GCN: h1 = relu(adj @ (x @ W1) + b1); h2 = relu(adj @ (h1 @ W2) + b2)
//      out[b] = (sum_{n<len[b]} h2[b,n,:] / len[b]) @ Wl + bl
// B=64, N=1024, NFEAT=512, NHID1=1024, NHID2=512
//
// All GEMMs in NT form: C[m][n] = sum_k A[m][k] * Bt[n][k]
//   A row-major [M,K], Bt row-major [N,K]. Both LDS tiles [rows][K-chunk],
//   both MFMA fragments contiguous ds_read_b128 (m92/m97 verified layout).
// R1: pool split into 2 well-parallelized stages (was 310us @ 2.6% occ);
//     transpose_cvt now LDS-tiled (coalesced both sides).
// ---------------------------------------------------------------------------

typedef short bf16x8 __attribute__((ext_vector_type(8)));
typedef short s16x4 __attribute__((ext_vector_type(4)));
typedef float f32x4 __attribute__((ext_vector_type(4)));

#define BM 128
#define BN 128
#define BK 32

__device__ __forceinline__ unsigned short f2bf(float f) {
    union { float f; unsigned u; } v; v.f = f;
    unsigned r = v.u + 0x7fffu + ((v.u >> 16) & 1u);   // RNE
    return (unsigned short)(r >> 16);
}
__device__ __forceinline__ float bf2f(unsigned short h) {
    union { unsigned u; float f; } v; v.u = ((unsigned)h) << 16;
    return v.f;
}

typedef const __attribute__((address_space(1))) void* gp1_t;
typedef __attribute__((address_space(3))) void* lp3_t;

__device__ __forceinline__ void ldsload16(const void* g, void* l) {
    // dest = wave-uniform LDS base + lane*16 (HW semantics)
    __builtin_amdgcn_global_load_lds((gp1_t)(uintptr_t)g,
                                     (lp3_t)(unsigned)(uintptr_t)l,
                                     16, 0, 0);
}

// NT GEMM: C = A(MxK,row) * Bt(NxK,row)^T, bf16 in/out, fp32 accumulate.
// SPLIT:  C index (m, nf) -> nf=b*1024+n stored at b*splitStride + m*1024 + n
// !SPLIT: C index (m, n)  -> z*cStride + m*N + n, optional bias[n] + relu
template<bool BIASRELU, bool SPLIT>
__global__ __launch_bounds__(256, 3)
void gemm_nt(const short* __restrict__ A, const short* __restrict__ B,
             short* __restrict__ C, const float* __restrict__ bias,
             int M, int N, int K,
             long long aStride, long long bStride, long long cStride,
             long long splitStride)
{
    __shared__ short As[BM * BK];   // 8 KB
    __shared__ short Bs[BN * BK];   // 8 KB

    const int tid  = threadIdx.x;
    const int wave = tid >> 6;
    const int lane = tid & 63;
    const int wm   = wave >> 1;       // 0..1
    const int wn   = wave & 1;        // 0..1
    const int quad = lane >> 4;       // 0..3
    const int l16  = lane & 15;

    const int bM = blockIdx.y * BM;
    const int bN = blockIdx.x * BN;
    const int z  = blockIdx.z;
    A += (long long)z * aStride;
    B += (long long)z * bStride;

    // staging: each lane loads 16B (8 bf16); wave covers 16 rows x 32 cols
    const int srow = lane >> 2;        // 0..15
    const int scol = (lane & 3) * 8;   // 0,8,16,24
    const short* Ag = A + (long long)(bM + wave * 16 + srow) * K + scol;
    const short* Bg = B + (long long)(bN + wave * 16 + srow) * K + scol;
    short* Asl = &As[(wave * 16) * BK];   // wave-uniform LDS base
    short* Bsl = &Bs[(wave * 16) * BK];

    f32x4 acc[4][4];
#pragma unroll
    for (int i = 0; i < 4; i++)
#pragma unroll
        for (int j = 0; j < 4; j++) acc[i][j] = (f32x4)0.0f;

    for (int k0 = 0; k0 < K; k0 += BK) {
        ldsload16(Ag + k0, Asl);
        ldsload16(Ag + (long long)64 * K + k0, Asl + 64 * BK);
        ldsload16(Bg + k0, Bsl);
        ldsload16(Bg + (long long)64 * K + k0, Bsl + 64 * BK);
        __syncthreads();

        bf16x8 af[4], bfr[4];
#pragma unroll
        for (int i = 0; i < 4; i++)
            af[i] = *(const bf16x8*)&As[(wm * 64 + i * 16 + l16) * BK + quad * 8];
#pragma unroll
        for (int j = 0; j < 4; j++)
            bfr[j] = *(const bf16x8*)&Bs[(wn * 64 + j * 16 + l16) * BK + quad * 8];
#pragma unroll
        for (int i = 0; i < 4; i++)
#pragma unroll
            for (int j = 0; j < 4; j++)
                acc[i][j] = __builtin_amdgcn_mfma_f32_16x16x32_bf16(
                    af[i], bfr[j], acc[i][j], 0, 0, 0);
        __syncthreads();
    }

    // Epilogue. C/D layout: col(n)=lane&15, row(m)=quad*4+reg  [m89/m91]
#pragma unroll
    for (int i = 0; i < 4; i++) {
        const int row0 = bM + wm * 64 + i * 16 + quad * 4;
#pragma unroll
        for (int j = 0; j < 4; j++) {
            const int col = bN + wn * 64 + j * 16 + l16;
            float bv = 0.0f;
            if (BIASRELU) bv = bias[col];
#pragma unroll
            for (int r = 0; r < 4; r++) {
                float val = acc[i][j][r];
                if (BIASRELU) val = fmaxf(val + bv, 0.0f);
                long long addr;
                if (SPLIT) {
                    const int bb = col >> 10;
                    const int n  = col & 1023;
                    addr = (long long)bb * splitStride
                         + (long long)(row0 + r) * 1024 + n;
                } else {
                    addr = (long long)z * cStride
                         + (long long)(row0 + r) * N + col;
                }
                C[addr] = (short)f2bf(val);
            }
        }
    }
}

__global__ void cvt_f32_bf16(const float4* __restrict__ in,
                             s16x4* __restrict__ out, int n4)
{
    int i = blockIdx.x * 256 + threadIdx.x;
    if (i < n4) {
        float4 v = in[i];
        s16x4 o;
        o.x = (short)f2bf(v.x); o.y = (short)f2bf(v.y);
        o.z = (short)f2bf(v.z); o.w = (short)f2bf(v.w);
        out[i] = o;
    }
}

// in[R][C] fp32 -> out[C][R] bf16, 32x32 LDS-tiled (coalesced both sides)
__global__ void transpose_cvt(const float* __restrict__ in,
                              short* __restrict__ out, int R, int C)
{
    __shared__ float tile[32][33];
    const int bc = blockIdx.x * 32;        // col-block in input
    const int br = blockIdx.y * 32;        // row-block in input
    const int tx = threadIdx.x & 31;
    const int ty = threadIdx.x >> 5;       // 0..7
#pragma unroll
    for (int i = 0; i < 32; i += 8)
        tile[ty + i][tx] = in[(long long)(br + ty + i) * C + bc + tx];
    __syncthreads();
#pragma unroll
    for (int i = 0; i < 32; i += 8)
        out[(long long)(bc + ty + i) * R + br + tx] = (short)f2bf(tile[tx][ty + i]);
}

// stage 1: partial column-sums of h2 over 128-row chunks, masked by length
// part layout: [b][chunk(8)][512] fp32
__global__ void pool_partial(const short* __restrict__ h2,
                             const int* __restrict__ length,
                             float* __restrict__ part)
{
    const int b = blockIdx.y;
    const int chunk = blockIdx.x;          // 0..7
    const int t = threadIdx.x;             // 0..255, 2 channels each
    const int len = length[b];
    const int r0 = chunk * 128;
    const int r1 = min(r0 + 128, len);
    const unsigned* p = (const unsigned*)(h2 + (long long)b * 1024 * 512);
    float s0 = 0.0f, s1 = 0.0f;
    for (int r = r0; r < r1; r++) {
        unsigned v = p[r * 256 + t];
        s0 += bf2f((unsigned short)(v & 0xffffu));
        s1 += bf2f((unsigned short)(v >> 16));
    }
    float2 o; o.x = s0; o.y = s1;
    ((float2*)part)[(b * 8 + chunk) * 256 + t] = o;
}

// stage 2: sum 8 partials, dot with Wl, divide by len, add bl
__global__ void pool_final2(const float* __restrict__ part,
                            const int* __restrict__ length,
                            const float* __restrict__ Wl,
                            const float* __restrict__ bl,
                            float* __restrict__ out)
{
    const int b = blockIdx.x;
    const int t = threadIdx.x;             // 0..255
    float s0 = 0.0f, s1 = 0.0f;
#pragma unroll
    for (int c = 0; c < 8; c++) {
        float2 v = ((const float2*)part)[(b * 8 + c) * 256 + t];
        s0 += v.x; s1 += v.y;
    }
    float v = s0 * Wl[2 * t] + s1 * Wl[2 * t + 1];
#pragma unroll
    for (int off = 32; off > 0; off >>= 1) v += __shfl_down(v, off);
    __shared__ float wsum[4];
    if ((t & 63) == 0) wsum[t >> 6] = v;
    __syncthreads();
    if (t == 0) {
        float s = wsum[0] + wsum[1] + wsum[2] + wsum[3];
        out[b] = s / (float)length[b] + bl[0];
    }
}

extern "C" void kernel_launch(void* const* d_in, const int* in_sizes, int n_in,
                              void* d_out, int out_size, void* d_ws, size_t ws_size,
                              hipStream_t stream)
{
    const float* x    = (const float*)d_in[0];   // [64,1024,512]
    const float* adj  = (const float*)d_in[1];   // [64,1024,1024]
    const int*   len  = (const int*)d_in[2];     // [64]
    const float* W1   = (const float*)d_in[3];   // [512,1024]
    const float* b1   = (const float*)d_in[4];   // [1024]
    const float* W2   = (const float*)d_in[5];   // [1024,512]
    const float* b2   = (const float*)d_in[6];   // [512]
    const float* Wl   = (const float*)d_in[7];   // [512]
    const float* bl   = (const float*)d_in[8];   // [1]
    float* out = (float*)d_out;

    // workspace layout (450 MiB total)
    char* ws = (char*)d_ws;
    short* adjB  = (short*)(ws);                         // 134217728 B
    short* xS2T  = (short*)(ws + 134217728LL);           //  67108864 B (x_bf16, later S2T, later pool partials)
    short* W1T   = (short*)(ws + 201326592LL);           //   1048576 B
    short* W2T   = (short*)(ws + 202375168LL);           //   1048576 B
    short* S1Th2 = (short*)(ws + 203423744LL);           // 134217728 B (S1T, later h2)
    short* h1    = (short*)(ws + 337641472LL);           // 134217728 B
    float* part  = (float*)(ws + 134217728LL + 33554432LL); // back half of xS2T region (S2T uses first 32MB)

    // conversions
    cvt_f32_bf16<<<65536, 256, 0, stream>>>((const float4*)adj, (s16x4*)adjB, 16777216);
    cvt_f32_bf16<<<32768, 256, 0, stream>>>((const float4*)x,   (s16x4*)xS2T,  8388608);
    transpose_cvt<<<dim3(32, 16), 256, 0, stream>>>(W1, W1T, 512, 1024);   // -> [1024,512]
    transpose_cvt<<<dim3(16, 32), 256, 0, stream>>>(W2, W2T, 1024, 512);   // -> [512,1024]

    // GEMM1 (transposed): S1T[b][h][n] = sum_f W1T[h][f] * x[b*1024+n][f]
    gemm_nt<false, true><<<dim3(512, 8, 1), 256, 0, stream>>>(
        W1T, xS2T, S1Th2, nullptr, 1024, 65536, 512, 0, 0, 0, 1048576LL);

    // GEMM2: h1[b][i][h] = relu(sum_j adj[b][i][j] * S1T[b][h][j] + b1[h])
    gemm_nt<true, false><<<dim3(8, 8, 64), 256, 0, stream>>>(
        adjB, S1Th2, h1, b1, 1024, 1024, 1024, 1048576LL, 1048576LL, 1048576LL, 0);

    // GEMM3 (transposed): S2T[b][h2][n] = sum_h W2T[h2][h] * h1[b*1024+n][h]
    // S2T occupies first 32 MB of the xS2T region (x_bf16 no longer needed)
    gemm_nt<false, true><<<dim3(512, 4, 1), 256, 0, stream>>>(
        W2T, h1, xS2T, nullptr, 512, 65536, 1024, 0, 0, 0, 524288LL);

    // GEMM4: h2[b][i][h2] = relu(sum_j adj[b][i][j] * S2T[b][h2][j] + b2[h2])
    gemm_nt<true, false><<<dim3(4, 8, 64), 256, 0, stream>>>(
        adjB, xS2T, S1Th2, b2, 1024, 512, 1024, 1048576LL, 524288LL, 524288LL, 0);

    // pool: stage 1 (512 blocks) + stage 2 (tiny)
    pool_partial<<<dim3(8, 64), 256, 0, stream>>>(S1Th2, len, part);
    pool_final2<<<64, 256, 0, stream>>>(part, len, Wl, bl, out);
}